// Round 5
// baseline (125.810 us; speedup 1.0000x reference)
//
#include <hip/hip_runtime.h>

// Problem constants (match reference)
#define VOCABN 100
#define EMBEDN 16
#define STATEN 7
#define OUTN   10
#define BATCHN 4096
#define SEQT   512
#define L2E 1.44269504088896340736f

typedef float v2f __attribute__((ext_vector_type(2)));

// v_exp_f32 / v_rcp_f32 saturate correctly at inf/0 -> gate forms below are
// exact at the extremes.
__device__ __forceinline__ float fexp2(float x){ float r; asm("v_exp_f32 %0, %1":"=v"(r):"v"(x)); return r; }
__device__ __forceinline__ float frcp (float x){ float r; asm("v_rcp_f32 %0, %1":"=v"(r):"v"(x)); return r; }

// DPP helpers. row_ror:n = 0x120+n (16-lane ring); quad_perm [1,0,3,2] = 0xB1.
template<int C> __device__ __forceinline__ int dppi(int x){
  return __builtin_amdgcn_update_dpp(0, x, C, 0xF, 0xF, true);
}
template<int C> __device__ __forceinline__ float dppf(float x){
  return __int_as_float(__builtin_amdgcn_update_dpp(0, __float_as_int(x), C, 0xF, 0xF, true));
}

// ---------------------------------------------------------------------------
// Kernel A: embW2[v][pos] = pre-scaled gate pre-activations, pos = s*2+p.
// p0 -> gates (i,f), p1 -> gates (g,o). Scales: i,f,o: -log2e; g: +2log2e.
// Pad state s=7 (pos 14,15) -> zeros.
// ---------------------------------------------------------------------------
__global__ void embw_kernel(const float* __restrict__ emb, const float* __restrict__ W,
                            const float* __restrict__ b, float* __restrict__ embw){
  int v = blockIdx.x, j = threadIdx.x;          // j 0..31
  int pos = j >> 1, g2 = j & 1;
  int s = pos >> 1, p = pos & 1, gate = p*2 + g2;
  float val = 0.0f;
  if (s < STATEN) {
    int col = gate*STATEN + s;
    val = b[col];
    #pragma unroll
    for (int e = 0; e < EMBEDN; ++e) val = fmaf(emb[v*EMBEDN+e], W[e*28+col], val);
    val *= (gate == 2) ? (2.0f*L2E) : (-L2E);
  }
  embw[v*32 + pos*2 + g2] = val;
}

// ---------------------------------------------------------------------------
// Kernel B: producer/consumer with barrier-paired double buffer + 2-way ILP.
// Block = 128 thr = 2 waves, 8 chains (batch rows) per block.
// Wave0 (producer): 4 groups x 16 lanes; each group runs TWO independent
//   chains (A = b0+g, B = b0+4+g) interleaved in the instruction stream so
//   chain B's issue fills chain A's dependence stalls (and vice versa).
//   Lane (s=pos>>1, p=pos&1) computes gate cols (i,f)[p0] / (g,o)[p1]; h is
//   broadcast by a depth-1 row_ror DPP net; weights pre-permuted by the
//   discovered sigma and pre-scaled (C tracked in 2*log2e*c domain).
// Wave1 (consumer): 64 lanes = 8 chains x 8 timesteps; each lane computes the
//   full dense+softmax for one (chain, timestep) of the octet. No cross-lane.
// Sync: octet-granular paired __syncthreads() + 2-slot hring. Producer writes
//   slot m&1 between barriers m-1 and m; consumer reads it between barriers m
//   and m+1; producer re-writes that slot only after barrier m+1. Safe by
//   construction (round-4's atomic handshake had a rare ordering escape).
// ---------------------------------------------------------------------------
__global__ void __launch_bounds__(128)
lstm_kernel(const int* __restrict__ tokens, const float* __restrict__ embw,
            const float* __restrict__ U, const float* __restrict__ Wd,
            const float* __restrict__ bdv, float* __restrict__ out){
  __shared__ float embW_s[VOCABN*32];     // 12.8 KB
  __shared__ int   tok_s[8*520];          // 16.6 KB (+pads for over-read)
  __shared__ float hring[2*8*8*16];       // 8 KB: [slot2][u8][gch8][pos16]

  const int tid = threadIdx.x;
  const int b0 = blockIdx.x*8;

  for (int i=tid;i<VOCABN*8;i+=128) ((float4*)embW_s)[i]=((const float4*)embw)[i];
  for (int i=tid;i<8*128;i+=128){ int r=i>>7,c4=i&127;
    int4 v=((const int4*)(tokens+(size_t)(b0+r)*SEQT))[c4];
    *((int4*)&tok_s[r*520+c4*4])=v; }
  if (tid<8){ tok_s[tid*520+512]=0; tok_s[tid*520+513]=0; tok_s[tid*520+514]=0; }
  __syncthreads();

  if (tid < 64) {
    // ===================== producer: 2 chains per lane =====================
    const int pos=tid&15, g=tid>>4, s=pos>>1, p=pos&1;

    // sigma discovery: run own state id through the exact broadcast net
    int sg[8];
    sg[0]=s;
    sg[1]=dppi<0x122>(s); sg[2]=dppi<0x124>(s); sg[3]=dppi<0x126>(s);
    sg[4]=dppi<0x128>(s); sg[5]=dppi<0x12A>(s); sg[6]=dppi<0x12C>(s); sg[7]=dppi<0x12E>(s);

    // recurrent weights: packed {colA,colB}, pre-permuted, pre-scaled (shared A/B)
    v2f Ucp[8];
    {
      const int gA=p*2, gB=p*2+1;
      const float sA = (gA==2)?(2.0f*L2E):(-L2E);
      const float sB = (gB==2)?(2.0f*L2E):(-L2E);
      #pragma unroll
      for (int k=0;k<8;++k){
        int sk=sg[k]; bool vld=(sk<STATEN)&&(s<STATEN);
        Ucp[k].x = vld ? U[sk*28+gA*7+s]*sA : 0.0f;
        Ucp[k].y = vld ? U[sk*28+gB*7+s]*sB : 0.0f;
      }
    }

    // one LSTM step: h,Cc in-place; pf0 = pre-scaled embW row for this step
    auto STEP=[&](float& h, float& Cc, const v2f& pf0){
      float r0=h;
      float r1=dppf<0x122>(h), r2=dppf<0x124>(h), r3=dppf<0x126>(h);
      float r4=dppf<0x128>(h), r5=dppf<0x12A>(h), r6=dppf<0x12C>(h), r7=dppf<0x12E>(h);
      v2f z01=__builtin_elementwise_fma((v2f){r1,r1},Ucp[1],
              __builtin_elementwise_fma((v2f){r0,r0},Ucp[0],pf0));
      v2f z23=__builtin_elementwise_fma((v2f){r3,r3},Ucp[3],(v2f){r2,r2}*Ucp[2]);
      v2f z45=__builtin_elementwise_fma((v2f){r5,r5},Ucp[5],(v2f){r4,r4}*Ucp[4]);
      v2f z67=__builtin_elementwise_fma((v2f){r7,r7},Ucp[7],(v2f){r6,r6}*Ucp[6]);
      v2f zv=(z01+z23)+(z45+z67);
      // p0: gA=i, gB=f ; p1: gA=rcp-part of g, gB=o
      float gA=frcp(1.0f+fexp2(zv.x));
      float gB=frcp(1.0f+fexp2(zv.y));
      float gg_s=__builtin_fmaf(gA,-4.0f*L2E,2.0f*L2E); // 2L2E*tanh(zg) on p1
      float gg_x=dppf<0xB1>(gg_s);                      // p0 <- p1
      float go_x=dppf<0xB1>(gB);                        // p0 <- p1's o
      Cc=__builtin_fmaf(gB,Cc,gA*gg_x);                 // valid on p0 (2L2E*c)
      float rcpC=frcp(1.0f+fexp2(Cc));                  // valid on p0
      float rcpC_x=dppf<0xB1>(rcpC);                    // p1 <- p0
      float go_u = p ? gB     : go_x;
      float rc_u = p ? rcpC_x : rcpC;
      h=__builtin_fmaf(-2.0f*go_u, rc_u, go_u);         // h = o*tanh(c)
    };

    const int* trA=&tok_s[g*520];
    const int* trB=&tok_s[(g+4)*520];

    // prefetch queues per chain: embW depth-2, token depth-3
    int tkA2=trA[2], tkB2=trB[2];
    v2f pfA0=*(const v2f*)&embW_s[trA[0]*32+pos*2];
    v2f pfA1=*(const v2f*)&embW_s[trA[1]*32+pos*2];
    v2f pfB0=*(const v2f*)&embW_s[trB[0]*32+pos*2];
    v2f pfB1=*(const v2f*)&embW_s[trB[1]*32+pos*2];
    float CcA=0.0f,hA=0.0f,CcB=0.0f,hB=0.0f;

    for (int m=0;m<64;++m){
      float* hslot=&hring[(m&1)*1024];
      #pragma unroll
      for (int u=0;u<8;++u){
        const int t=m*8+u;
        v2f pfA2=*(const v2f*)&embW_s[tkA2*32+pos*2];
        v2f pfB2=*(const v2f*)&embW_s[tkB2*32+pos*2];
        int tkA3=trA[t+3], tkB3=trB[t+3];

        STEP(hA,CcA,pfA0);                  // two independent chains:
        STEP(hB,CcB,pfB0);                  // B's issue fills A's stalls
        hslot[u*128 + g*16 + pos]=hA;
        hslot[u*128 + (g+4)*16 + pos]=hB;

        pfA0=pfA1; pfA1=pfA2; tkA2=tkA3;
        pfB0=pfB1; pfB1=pfB2; tkB2=tkB3;
      }
      __syncthreads();   // publish octet m (slot m&1) to the consumer wave
    }
  } else {
    // ===================== consumer: dense + softmax =====================
    const int lq=tid-64, ch=lq>>3, tq=lq&7;  // chain 0..7, timestep-in-octet

    // dense weights, natural state order, pre-scaled by log2e
    float Wdc[7][10], bdr[10];
    #pragma unroll
    for (int s2=0;s2<7;++s2)
      #pragma unroll
      for (int o=0;o<OUTN;++o) Wdc[s2][o]=Wd[s2*10+o]*L2E;
    #pragma unroll
    for (int o=0;o<OUTN;++o) bdr[o]=bdv[o]*L2E;

    float* outp = out + ((size_t)(b0+ch)*SEQT + tq)*OUTN;

    for (int m=0;m<64;++m){
      __syncthreads();   // wait for octet m (slot m&1)
      const float* hp=&hring[(m&1)*1024 + tq*128 + ch*16];
      float h0=hp[0], h1=hp[2], h2=hp[4], h3=hp[6];
      float h4=hp[8], h5=hp[10], h6=hp[12];

      float lg[10];
      #pragma unroll
      for (int o=0;o<OUTN;++o){
        float a=bdr[o];
        a=__builtin_fmaf(h0,Wdc[0][o],a); a=__builtin_fmaf(h1,Wdc[1][o],a);
        a=__builtin_fmaf(h2,Wdc[2][o],a); a=__builtin_fmaf(h3,Wdc[3][o],a);
        a=__builtin_fmaf(h4,Wdc[4][o],a); a=__builtin_fmaf(h5,Wdc[5][o],a);
        a=__builtin_fmaf(h6,Wdc[6][o],a);
        lg[o]=a;
      }
      float mx=lg[0];
      #pragma unroll
      for (int o=1;o<OUTN;++o) mx=fmaxf(mx,lg[o]);
      float e[10], sm=0.0f;
      #pragma unroll
      for (int o=0;o<OUTN;++o){ e[o]=fexp2(lg[o]-mx); sm+=e[o]; }
      float rs=frcp(sm);
      float2* op=(float2*)outp;
      op[0]=make_float2(e[0]*rs,e[1]*rs);
      op[1]=make_float2(e[2]*rs,e[3]*rs);
      op[2]=make_float2(e[4]*rs,e[5]*rs);
      op[3]=make_float2(e[6]*rs,e[7]*rs);
      op[4]=make_float2(e[8]*rs,e[9]*rs);
      outp += 8*OUTN;
    }
  }
}

// ---------------------------------------------------------------------------
// inputs: 0 tokens 1 emb 2 W 3 U 4 b 5 Wd 6 bd ; out f32 B*T*10.
// d_ws: 12800 B for the pre-scaled embW table (rewritten every call).
// ---------------------------------------------------------------------------
extern "C" void kernel_launch(void* const* d_in, const int* in_sizes, int n_in,
                              void* d_out, int out_size, void* d_ws, size_t ws_size,
                              hipStream_t stream) {
  const int*   tokens = (const int*)d_in[0];
  const float* emb    = (const float*)d_in[1];
  const float* W      = (const float*)d_in[2];
  const float* U      = (const float*)d_in[3];
  const float* b      = (const float*)d_in[4];
  const float* Wd     = (const float*)d_in[5];
  const float* bd     = (const float*)d_in[6];
  float* outp = (float*)d_out;
  float* embw = (float*)d_ws;

  embw_kernel<<<dim3(VOCABN), dim3(32), 0, stream>>>(emb, W, b, embw);
  lstm_kernel<<<dim3(BATCHN/8), dim3(128), 0, stream>>>(tokens, embw, U, Wd, bd, outp);
}